// Round 12
// baseline (157.235 us; speedup 1.0000x reference)
//
#include <hip/hip_runtime.h>
#include <math.h>

#define NN   4096
#define DM   256
#define NH   8
#define HDIM 32
#define NE   65536
#define ROWW 64
#define QS   0.25503473f   // log2(e)/sqrt(32)

typedef unsigned short u16t;
typedef unsigned int   u32t;
typedef unsigned long long u64t;
typedef __attribute__((ext_vector_type(8))) short bf16x8;
typedef __attribute__((ext_vector_type(4))) float f32x4;

__device__ __forceinline__ u16t f2bf(float f){            // RNE
  u32t x; __builtin_memcpy(&x,&f,4);
  u32t r=(x+0x7fffu+((x>>16)&1u))>>16;
  return (u16t)r;
}
__device__ __forceinline__ float fexp2(float x){
#if __has_builtin(__builtin_amdgcn_exp2f)
  return __builtin_amdgcn_exp2f(x);
#else
  return exp2f(x);
#endif
}
__device__ __forceinline__ int sbfe1(u32t v, int pos){    // 0 or -1 from bit
#if __has_builtin(__builtin_amdgcn_sbfe)
  return __builtin_amdgcn_sbfe((int)v, pos, 1);
#else
  return ((int)(v << (31-pos))) >> 31;
#endif
}
// truncating bf16 pair pack: lo16 = hi16(a), hi16 = hi16(b)
__device__ __forceinline__ u32t pk2t(float a, float b){
  u32t xa, xb;
  __builtin_memcpy(&xa,&a,4); __builtin_memcpy(&xb,&b,4);
#if __has_builtin(__builtin_amdgcn_perm)
  return __builtin_amdgcn_perm(xb, xa, 0x07060302u);
#else
  return (xa>>16) | (xb & 0xffff0000u);
#endif
}
__device__ __forceinline__ void gl2lds16(const void* g, void* l){
  auto gp = (const __attribute__((address_space(1))) u32t*)(unsigned long long)g;
  auto lp = (__attribute__((address_space(3))) u32t*)(u32t)(unsigned long long)l;
  __builtin_amdgcn_global_load_lds(gp, lp, 16, 0, 0);
}

// ---------------- K0: W transposes + bias + x->bf16 + edge bitmask ----------------
// Wo gets its k-rows PERMUTED: stored p=h*32+2i <- orig h*32+i ; p=h*32+2i+1 <- orig h*32+16+i
__global__ __launch_bounds__(256) void k0_kernel(
    const float* __restrict__ Wq, const float* __restrict__ bq,
    const float* __restrict__ Wk, const float* __restrict__ bk,
    const float* __restrict__ Wv, const float* __restrict__ bv,
    const float* __restrict__ Wo, const float* __restrict__ x,
    u16t* __restrict__ Wtb, float* __restrict__ bb, u16t* __restrict__ xb,
    const int* __restrict__ ei, u64t* __restrict__ A)
{
  const int b = blockIdx.x, tid = threadIdx.x;
  if (b < 64){
    __shared__ __align__(16) float Tf[64*64];
    const int mat = b>>4, t = b&15;
    const int k0 = (t>>2)*64, nc0 = (t&3)*64;
    const float* W = mat==0? Wq : (mat==1? Wk : (mat==2? Wv : Wo));
    const float scale = (mat==0) ? QS : 1.0f;
    #pragma unroll
    for (int i=0;i<4;i++){
      int c = i*256+tid;
      int kk = c>>4, ch = c&15;
      float4 v = *(const float4*)(W + (size_t)(k0+kk)*256 + nc0 + ch*4);
      *(float4*)&Tf[kk*64 + ch*4] = v;
    }
    __syncthreads();
    const int nn = tid>>2, kc = tid&3;
    u32t pk[8];
    if (mat == 3){
      #pragma unroll
      for (int p=0;p<8;p++){
        int q0 = kc*16 + 2*p, q1 = q0+1;
        int s0 = (q0 & 32) + ((q0&31)>>1) + ((q0&1)<<4);
        int s1 = (q1 & 32) + ((q1&31)>>1) + ((q1&1)<<4);
        pk[p] = (u32t)f2bf(Tf[s0*64+nn]) | ((u32t)f2bf(Tf[s1*64+nn])<<16);
      }
    } else {
      #pragma unroll
      for (int p=0;p<8;p++){
        float a  = Tf[(kc*16+2*p  )*64 + nn]*scale;
        float b2 = Tf[(kc*16+2*p+1)*64 + nn]*scale;
        pk[p] = (u32t)f2bf(a) | ((u32t)f2bf(b2)<<16);
      }
    }
    u16t* o = Wtb + ((size_t)mat*256 + nc0 + nn)*256 + k0 + kc*16;
    *(uint4*)o     = make_uint4(pk[0],pk[1],pk[2],pk[3]);
    *(uint4*)(o+8) = make_uint4(pk[4],pk[5],pk[6],pk[7]);
  } else if (b == 64){
    #pragma unroll
    for (int i=0;i<3;i++){
      int j = i*256 + tid;
      bb[j] = (j<256) ? bq[j]*QS : ((j<512) ? bk[j-256] : bv[j-512]);
    }
  } else if (b < 193){
    const int bi = b-65;
    #pragma unroll
    for (int i=0;i<8;i++){
      int idx = (bi*256+tid) + i*32768;   // float4 chunks, 262144 total
      float4 v = *(const float4*)(x + (size_t)idx*4);
      u32t p0 = (u32t)f2bf(v.x) | ((u32t)f2bf(v.y)<<16);
      u32t p1 = (u32t)f2bf(v.z) | ((u32t)f2bf(v.w)<<16);
      *(uint2*)(xb + (size_t)idx*4) = make_uint2(p0,p1);
    }
  } else {
    int e = (b-193)*256 + tid;
    int s = ei[e];
    int d = ei[NE + e];
    atomicOr(&A[(size_t)s*ROWW + (d>>6)], 1ull<<(d&63));
    atomicOr(&A[(size_t)d*ROWW + (s>>6)], 1ull<<(s&63));
    if (e < NN) atomicOr(&A[(size_t)e*ROWW + (e>>6)], 1ull<<(e&63));
  }
}

// ---------------- K1: QKV GEMM (64M x 128N, +direct V^T store) fused with reach-2 ----------------
__global__ __launch_bounds__(256) void k1_kernel(
    const u16t* __restrict__ xb, const u16t* __restrict__ Wtb,
    const float* __restrict__ bb, u16t* __restrict__ QKV, u16t* __restrict__ Vth,
    const u64t* __restrict__ A, u64t* __restrict__ MT)
{
  __shared__ __align__(16) u16t Xs[64*256];    // 32KB; reach2 + epilogue alias into it
  __shared__ int cnt;
  const int bx = blockIdx.x, tid = threadIdx.x;
  if (bx >= 384){
    const int n = bx - 384;
    u16t* list = Xs;                       // [0..8KB)
    u64t* accs = (u64t*)(Xs + 8192);       // [16KB..18KB)
    const int t = tid & 63;
    const int g = tid >> 6;
    if (tid==0) cnt=0;
    __syncthreads();
    if (tid < ROWW){
      u64t w = A[(size_t)n*ROWW + tid];
      int base = tid*64;
      while (w){
        int b = __builtin_ctzll(w);
        w &= w-1;
        int i = atomicAdd(&cnt,1);
        list[i] = (u16t)(base+b);
      }
    }
    __syncthreads();
    const int c = cnt;
    u64t acc = 0;
    int i = g;
    for (; i+12 < c; i += 16){
      u64t a0 = A[(size_t)list[i   ]*ROWW + t];
      u64t a1 = A[(size_t)list[i+4 ]*ROWW + t];
      u64t a2 = A[(size_t)list[i+8 ]*ROWW + t];
      u64t a3 = A[(size_t)list[i+12]*ROWW + t];
      acc |= a0 | a1 | a2 | a3;
    }
    for (; i < c; i += 4){
      acc |= A[(size_t)list[i]*ROWW + t];
    }
    accs[tid] = acc;
    __syncthreads();
    if (tid < ROWW){
      u64t a = accs[tid] | accs[64+tid] | accs[128+tid] | accs[192+tid];
      MT[(size_t)tid*NN + n] = a;          // transposed: word-major
    }
    return;
  }
  const int w = tid>>6, lane = tid&63, l15 = lane&15, quad = lane>>4;
  const int mt = bx / 6;
  const int nt = bx % 6;
  const int m0 = mt*64, n0 = nt*128;
  #pragma unroll
  for (int i=0;i<8;i++){
    int c = i*256 + tid;
    int row = c>>5, pc = c&31;
    int lc = pc ^ (row&7);
    gl2lds16(xb + (size_t)(m0+row)*256 + lc*8, &Xs[(size_t)(i*256 + w*64)*8]);
  }
  __syncthreads();
  bf16x8 afr[8];
  {
    const int row = w*16 + l15;
    #pragma unroll
    for (int kc=0;kc<8;kc++){
      const int phys = (kc*4+quad) ^ (row&7);
      uint4 t = *(const uint4*)&Xs[row*256 + phys*8];
      __builtin_memcpy(&afr[kc], &t, 16);
    }
  }
  f32x4 acc[8];
  #pragma unroll
  for (int nf=0;nf<8;nf++){
    float b2 = bb[n0 + nf*16 + l15];
    acc[nf] = (f32x4){b2,b2,b2,b2};
  }
  #pragma unroll
  for (int nf=0;nf<8;nf++){
    const u16t* Bp = Wtb + (size_t)(n0 + nf*16 + l15)*256 + quad*8;
    #pragma unroll
    for (int kc=0;kc<8;kc++){
      uint4 t = *(const uint4*)(Bp + kc*32);
      bf16x8 bfr; __builtin_memcpy(&bfr,&t,16);
      acc[nf] = __builtin_amdgcn_mfma_f32_16x16x32_bf16(afr[kc], bfr, acc[nf], 0,0,0);
    }
  }
  if (nt < 4){
    // LDS transpose -> coalesced row stores (Cs = 64 x 128 u16 = 16KB, aliases Xs)
    __syncthreads();
    u16t* Cs = Xs;
    #pragma unroll
    for (int nf=0;nf<8;nf++){
      const int col = nf*16 + l15;
      #pragma unroll
      for (int r=0;r<4;r++){
        Cs[(w*16+quad*4+r)*128 + col] = f2bf(acc[nf][r]);
      }
    }
    __syncthreads();
    #pragma unroll
    for (int i=0;i<4;i++){
      int id = i*256 + tid;
      int m = id>>4, c = id&15;
      uint4 v = *(const uint4*)&Cs[m*128 + c*8];
      *(uint4*)(QKV + (size_t)(m0+m)*512 + n0 + c*8) = v;
    }
  } else {
    // V^T: pack 4 consecutive m into one 8B store
    #pragma unroll
    for (int nf=0;nf<8;nf++){
      const int vcol = n0 - 512 + nf*16 + l15;   // 0..255 = h*32+d
      u32t a  = (u32t)f2bf(acc[nf][0]) | ((u32t)f2bf(acc[nf][1])<<16);
      u32t b2 = (u32t)f2bf(acc[nf][2]) | ((u32t)f2bf(acc[nf][3])<<16);
      *(uint2*)(Vth + (size_t)vcol*NN + m0 + w*16 + quad*4) = make_uint2(a,b2);
    }
  }
}

// ---------------- K2: flash attention, S^T + O^T scheme (no P LDS round-trip) ----------------
// grid 2048: h = bx&7, qt = (bx>>3)&31 (128 q-rows), eighth = bx>>8 (0..7); 8 k-tiles each.
// O^T via mfma(V^T-frag, P^T-frag): P^T's B-layout == S^T's C-layout (k-index bijection).
__global__ __launch_bounds__(256) void fattn_kernel(
    const u64t* __restrict__ MT, const u16t* __restrict__ QKV,
    const u16t* __restrict__ Vth,
    u32t* __restrict__ attB, float* __restrict__ Lp)
{
  __shared__ __align__(16) u16t Ks[2][64*HDIM];
  __shared__ __align__(16) u16t Vs[2][HDIM*64];
  __shared__ __align__(16) u64t Ms[2][128];

  const int tid  = threadIdx.x;
  const int w    = tid >> 6;
  const int lane = tid & 63;
  const int l15  = lane & 15;
  const int quad = lane >> 4;
  const int h    = blockIdx.x & 7;
  const int n0   = ((blockIdx.x >> 3) & 31) * 128;
  const int eighth = blockIdx.x >> 8;
  const int kb   = eighth*8;
  const int ke   = kb+8;

  const u16t* Kg = QKV + 256 + h*HDIM;          // row-major stride 512
  const u16t* Vg = Vth + (size_t)h*HDIM*NN;
  const int kr = tid>>2, kqp = tid&3;
  const int kgo = kr*512 + (kqp ^ ((kr>>1)&3))*8;
  const int vr = tid>>3, vqp = tid&7;
  const int vgo = vr*NN + (vqp ^ (vr&7))*8;

  // Q B-operand frags for the two 64-row subtiles
  bf16x8 qf[2];
  #pragma unroll
  for (int s=0;s<2;s++){
    const u16t* qp = QKV + (size_t)(n0 + s*64 + w*16 + l15)*512 + h*HDIM + quad*8;
    uint4 t = *(const uint4*)qp;
    __builtin_memcpy(&qf[s], &t, 16);
  }
  bf16x8 ones8;
  {
    const short o = (short)0x3f80;      // bf16 1.0
    ones8 = (bf16x8){o,o,o,o,o,o,o,o};
  }

  // Oacc[s][dh] holds O^T: row d = dh*16 + quad*4 + r, col q = l15
  f32x4 Oacc[2][2] = {{{0.f,0.f,0.f,0.f},{0.f,0.f,0.f,0.f}},
                      {{0.f,0.f,0.f,0.f},{0.f,0.f,0.f,0.f}}};
  f32x4 Lacc[2]    = {{0.f,0.f,0.f,0.f},{0.f,0.f,0.f,0.f}};
  const f32x4 zero = {0.f,0.f,0.f,0.f};

  #define STAGE(kt, buf) do { \
    gl2lds16(Kg + (size_t)(kt)*64*512 + kgo, &Ks[(buf)][w*512]); \
    gl2lds16(Vg + (size_t)(kt)*64 + vgo,  &Vs[(buf)][w*512]); \
    if (tid < 64) gl2lds16(MT + (size_t)(kt)*NN + n0 + tid*2, &Ms[(buf)][0]); \
  } while(0)

  STAGE(kb, kb&1);
  const int kswz = (l15>>1)&3;

  for (int kt=kb; kt<ke; ++kt){
    __syncthreads();
    if (kt+1 < ke) STAGE(kt+1, (kt+1)&1);
    const int buf = kt&1;

    // V^T A-operand frags (shared by both subtiles): pair gp covers groups 2gp,2gp+1
    // logical u16 col of group g starts at g*16+quad*4; chunk swizzle c^(row&7)
    bf16x8 vf[2][2];
    #pragma unroll
    for (int gp=0; gp<2; ++gp){
      #pragma unroll
      for (int dh=0; dh<2; ++dh){
        const int row = dh*16 + l15;
        const int half = (quad&1)*4;
        const u16t* v0 = &Vs[buf][row*64 + (((gp*4   + (quad>>1)) ^ (l15&7))<<3) + half];
        const u16t* v1 = &Vs[buf][row*64 + (((gp*4+2 + (quad>>1)) ^ (l15&7))<<3) + half];
        uint2 a = *(const uint2*)v0;
        uint2 b = *(const uint2*)v1;
        uint4 t = make_uint4(a.x, a.y, b.x, b.y);
        __builtin_memcpy(&vf[gp][dh], &t, 16);
      }
    }

    // per subtile: S^T, mask+exp, pack -> P^T B-frag, MFMA into O^T and L
    #pragma unroll
    for (int s=0;s<2;s++){
      f32x4 S[4];
      #pragma unroll
      for (int g=0; g<4; ++g){
        const u16t* kp = &Ks[buf][(g*16+l15)*HDIM + (quad ^ kswz)*8];
        uint4 t = *(const uint4*)kp;
        bf16x8 kf; __builtin_memcpy(&kf,&t,16);
        S[g] = __builtin_amdgcn_mfma_f32_16x16x32_bf16(kf, qf[s], zero, 0,0,0);
      }
      u64t mw = Ms[buf][s*64 + w*16 + l15] >> (quad*4);
      u32t slo = (u32t)mw, shi = (u32t)(mw>>32);
      #pragma unroll
      for (int g=0; g<4; ++g){
        const u32t sv = (g&2)? shi : slo;
        const int base = (g&1)*16;
        #pragma unroll
        for (int r=0;r<4;r++){
          float p = fexp2(S[g][r]);
          u32t pi; __builtin_memcpy(&pi,&p,4);
          pi &= (u32t)sbfe1(sv, base+r);
          __builtin_memcpy(&p,&pi,4);
          S[g][r] = p;
        }
      }
      #pragma unroll
      for (int gp=0; gp<2; ++gp){
        uint4 tb = make_uint4(pk2t(S[2*gp][0],  S[2*gp][1]),
                              pk2t(S[2*gp][2],  S[2*gp][3]),
                              pk2t(S[2*gp+1][0],S[2*gp+1][1]),
                              pk2t(S[2*gp+1][2],S[2*gp+1][3]));
        bf16x8 pb; __builtin_memcpy(&pb,&tb,16);
        Lacc[s]    = __builtin_amdgcn_mfma_f32_16x16x32_bf16(ones8,    pb, Lacc[s],    0,0,0);
        Oacc[s][0] = __builtin_amdgcn_mfma_f32_16x16x32_bf16(vf[gp][0], pb, Oacc[s][0], 0,0,0);
        Oacc[s][1] = __builtin_amdgcn_mfma_f32_16x16x32_bf16(vf[gp][1], pb, Oacc[s][1], 0,0,0);
      }
    }
  }
  #undef STAGE

  // epilogue: O^T -> coalesced uint4 stores; L[q] identical across regs
  #pragma unroll
  for (int s=0;s<2;s++){
    const int n = n0 + s*64 + w*16 + l15;
    if (quad == 0)
      Lp[(size_t)eighth*NH*NN + (size_t)h*NN + n] = Lacc[s][0];
    uint4 o;
    o.x = (u32t)f2bf(Oacc[s][0][0]) | ((u32t)f2bf(Oacc[s][1][0])<<16);
    o.y = (u32t)f2bf(Oacc[s][0][1]) | ((u32t)f2bf(Oacc[s][1][1])<<16);
    o.z = (u32t)f2bf(Oacc[s][0][2]) | ((u32t)f2bf(Oacc[s][1][2])<<16);
    o.w = (u32t)f2bf(Oacc[s][0][3]) | ((u32t)f2bf(Oacc[s][1][3])<<16);
    *(uint4*)&attB[((size_t)eighth*NN + n)*128 + h*16 + quad*4] = o;
  }
}

// ---------------- K3: merge 8 partials + out-proj (MFMA, permuted WoT) + residual + layernorm ----------------
__global__ __launch_bounds__(256) void outln_kernel(
    const u32t* __restrict__ attB, const float* __restrict__ Lp,
    const u16t* __restrict__ WoT, const float* __restrict__ bo,
    const float* __restrict__ x, const float* __restrict__ lnw, const float* __restrict__ lnb,
    float* __restrict__ out)
{
  __shared__ __align__(16) u16t As[16*256];
  __shared__ float Lr[8*16];
  __shared__ float red1[16][4], red2[16][4];
  const int tid = threadIdx.x;
  const int w = tid>>6, lane = tid&63, l15 = lane&15, quad = lane>>4;
  const int n0 = blockIdx.x*16;

  if (tid < 128){
    int hh = tid>>4, rr = tid&15;
    float l = 0.f;
    #pragma unroll
    for (int e=0;e<8;e++)
      l += Lp[(size_t)e*NH*NN + (size_t)hh*NN + n0+rr];
    Lr[tid] = 1.f/l;
  }
  __syncthreads();
  // merge 8 bf16-paired partials -> normalized bf16 As (permuted col order, swizzled)
  #pragma unroll
  for (int it=0; it<8; ++it){
    int e = it*256 + tid;           // 2048 = 16 rows x 128 u32
    int n = e>>7, j = e&127;
    float s0=0.f, s1=0.f;
    #pragma unroll
    for (int qq=0;qq<8;qq++){
      u32t u = attB[((size_t)qq*NN + n0+n)*128 + j];
      u32t ul = u<<16, uh = u & 0xffff0000u;
      float lo, hi;
      __builtin_memcpy(&lo,&ul,4); __builtin_memcpy(&hi,&uh,4);
      s0 += lo; s1 += hi;
    }
    float rinv = Lr[(j>>4)*16 + n];
    u32t pkd = pk2t(s0*rinv, s1*rinv);
    ((u32t*)As)[n*128 + ((j>>2) ^ (n&7))*4 + (j&3)] = pkd;
  }
  __syncthreads();

  bf16x8 afr[8];
  #pragma unroll
  for (int kc=0;kc<8;kc++){
    const int phys = (kc*4+quad) ^ (l15&7);
    uint4 t = *(const uint4*)&As[l15*256 + phys*8];
    __builtin_memcpy(&afr[kc], &t, 16);
  }
  f32x4 acc[4];
  #pragma unroll
  for (int nf=0;nf<4;nf++){
    const int col = w*64 + nf*16 + l15;
    float b2 = bo[col];
    acc[nf] = (f32x4){b2,b2,b2,b2};
    const u16t* Bp = WoT + (size_t)col*256 + quad*8;
    #pragma unroll
    for (int kc=0;kc<8;kc++){
      uint4 t = *(const uint4*)(Bp + kc*32);
      bf16x8 bfr; __builtin_memcpy(&bfr,&t,16);
      acc[nf] = __builtin_amdgcn_mfma_f32_16x16x32_bf16(afr[kc], bfr, acc[nf], 0,0,0);
    }
  }
  float ps1[4]={0,0,0,0}, ps2[4]={0,0,0,0};
  #pragma unroll
  for (int nf=0;nf<4;nf++){
    const int col = w*64 + nf*16 + l15;
    #pragma unroll
    for (int r=0;r<4;r++){
      float v = acc[nf][r] + x[(size_t)(n0+quad*4+r)*DM + col];
      acc[nf][r] = v;
      ps1[r] += v;
      ps2[r] += v*v;
    }
  }
  #pragma unroll
  for (int r=0;r<4;r++){
    ps1[r] += __shfl_xor(ps1[r],1); ps2[r] += __shfl_xor(ps2[r],1);
    ps1[r] += __shfl_xor(ps1[r],2); ps2[r] += __shfl_xor(ps2[r],2);
    ps1[r] += __shfl_xor(ps1[r],4); ps2[r] += __shfl_xor(ps2[r],4);
    ps1[r] += __shfl_xor(ps1[r],8); ps2[r] += __shfl_xor(ps2[r],8);
    if (l15==0){ red1[quad*4+r][w]=ps1[r]; red2[quad*4+r][w]=ps2[r]; }
  }
  __syncthreads();
  float mu[4], rs[4];
  #pragma unroll
  for (int r=0;r<4;r++){
    const int row = quad*4+r;
    float s1 = red1[row][0]+red1[row][1]+red1[row][2]+red1[row][3];
    float s2 = red2[row][0]+red2[row][1]+red2[row][2]+red2[row][3];
    mu[r] = s1*(1.0f/256.0f);
    float var = s2*(1.0f/256.0f) - mu[r]*mu[r];
    rs[r] = rsqrtf(var+1e-5f);
  }
  #pragma unroll
  for (int nf=0;nf<4;nf++){
    const int col = w*64 + nf*16 + l15;
    const float lw = lnw[col], lb = lnb[col];
    #pragma unroll
    for (int r=0;r<4;r++){
      out[(size_t)(n0+quad*4+r)*DM + col] = (acc[nf][r]-mu[r])*rs[r]*lw + lb;
    }
  }
}

extern "C" void kernel_launch(void* const* d_in, const int* in_sizes, int n_in,
                              void* d_out, int out_size, void* d_ws, size_t ws_size,
                              hipStream_t stream) {
  const float* x   = (const float*)d_in[0];
  const int*   ei  = (const int*  )d_in[1];
  const float* Wq  = (const float*)d_in[2];
  const float* bq  = (const float*)d_in[3];
  const float* Wk  = (const float*)d_in[4];
  const float* bk  = (const float*)d_in[5];
  const float* Wv  = (const float*)d_in[6];
  const float* bv  = (const float*)d_in[7];
  const float* Wo  = (const float*)d_in[8];
  const float* bo  = (const float*)d_in[9];
  const float* lnw = (const float*)d_in[10];
  const float* lnb = (const float*)d_in[11];

  char* ws = (char*)d_ws;
  u64t*  A    = (u64t*)(ws);                     // 0..2MB adjacency bits (memset)
  u64t*  MT   = (u64t*)(ws + (2u<<20));          // 2..4MB reach-2 bits, transposed [64][4096]
  u32t*  attB = (u32t*)(ws + (4u<<20));          // 4..20MB O^T partials [8][4096][128] u32 (bf16 pairs)
  u16t*  xb   = (u16t*)(ws + (4u<<20));          // alias attB[0..2MB): conv->gemm only
  u16t*  QKV  = (u16t*)(ws + (20u<<20));         // 20..24MB [4096][512] bf16 (Q|K)
  u16t*  Vth  = (u16t*)(ws + (24u<<20));         // 24..26MB [256][4096] bf16 V^T
  float* Lp   = (float*)(ws + (26u<<20));        // 26..27MB L partials [8][8][4096]
  u16t*  Wtb  = (u16t*)(ws + (27u<<20));         // 27..27.5MB W^T bf16 (4 mats)
  float* bb   = (float*)(ws + (27u<<20) + (512u<<10)); // bias fp32 (768)

  hipMemsetAsync(A, 0, (2u<<20), stream);
  k0_kernel  <<<449,  256, 0, stream>>>(Wq,bq, Wk,bk, Wv,bv, Wo, x, Wtb, bb, xb, ei, A);
  k1_kernel  <<<4480, 256, 0, stream>>>(xb, Wtb, bb, QKV, Vth, A, MT);
  fattn_kernel<<<2048, 256, 0, stream>>>(MT, QKV, Vth, attB, Lp);
  outln_kernel<<<256,  256, 0, stream>>>(attB, Lp, Wtb + (size_t)3*256*256, bo, x, lnw, lnb, (float*)d_out);
}

// Round 13
// 156.153 us; speedup vs baseline: 1.0069x; 1.0069x over previous
//
#include <hip/hip_runtime.h>
#include <math.h>

#define NN   4096
#define DM   256
#define NH   8
#define HDIM 32
#define NE   65536
#define ROWW 64
#define QS   0.25503473f   // log2(e)/sqrt(32)

typedef unsigned short u16t;
typedef unsigned int   u32t;
typedef unsigned long long u64t;
typedef __attribute__((ext_vector_type(8))) short bf16x8;
typedef __attribute__((ext_vector_type(4))) float f32x4;

__device__ __forceinline__ u16t f2bf(float f){            // RNE
  u32t x; __builtin_memcpy(&x,&f,4);
  u32t r=(x+0x7fffu+((x>>16)&1u))>>16;
  return (u16t)r;
}
__device__ __forceinline__ float fexp2(float x){
#if __has_builtin(__builtin_amdgcn_exp2f)
  return __builtin_amdgcn_exp2f(x);
#else
  return exp2f(x);
#endif
}
__device__ __forceinline__ int sbfe1(u32t v, int pos){    // 0 or -1 from bit
#if __has_builtin(__builtin_amdgcn_sbfe)
  return __builtin_amdgcn_sbfe((int)v, pos, 1);
#else
  return ((int)(v << (31-pos))) >> 31;
#endif
}
// truncating bf16 pair pack: lo16 = hi16(a), hi16 = hi16(b)
__device__ __forceinline__ u32t pk2t(float a, float b){
  u32t xa, xb;
  __builtin_memcpy(&xa,&a,4); __builtin_memcpy(&xb,&b,4);
#if __has_builtin(__builtin_amdgcn_perm)
  return __builtin_amdgcn_perm(xb, xa, 0x07060302u);
#else
  return (xa>>16) | (xb & 0xffff0000u);
#endif
}
__device__ __forceinline__ void gl2lds16(const void* g, void* l){
  auto gp = (const __attribute__((address_space(1))) u32t*)(unsigned long long)g;
  auto lp = (__attribute__((address_space(3))) u32t*)(u32t)(unsigned long long)l;
  __builtin_amdgcn_global_load_lds(gp, lp, 16, 0, 0);
}

// ---------------- K0: W transposes + bias + x->bf16 + edge bitmask ----------------
// Wo gets its k-rows PERMUTED: stored p=h*32+2i <- orig h*32+i ; p=h*32+2i+1 <- orig h*32+16+i
__global__ __launch_bounds__(256) void k0_kernel(
    const float* __restrict__ Wq, const float* __restrict__ bq,
    const float* __restrict__ Wk, const float* __restrict__ bk,
    const float* __restrict__ Wv, const float* __restrict__ bv,
    const float* __restrict__ Wo, const float* __restrict__ x,
    u16t* __restrict__ Wtb, float* __restrict__ bb, u16t* __restrict__ xb,
    const int* __restrict__ ei, u64t* __restrict__ A)
{
  const int b = blockIdx.x, tid = threadIdx.x;
  if (b < 64){
    __shared__ __align__(16) float Tf[64*64];
    const int mat = b>>4, t = b&15;
    const int k0 = (t>>2)*64, nc0 = (t&3)*64;
    const float* W = mat==0? Wq : (mat==1? Wk : (mat==2? Wv : Wo));
    const float scale = (mat==0) ? QS : 1.0f;
    #pragma unroll
    for (int i=0;i<4;i++){
      int c = i*256+tid;
      int kk = c>>4, ch = c&15;
      float4 v = *(const float4*)(W + (size_t)(k0+kk)*256 + nc0 + ch*4);
      *(float4*)&Tf[kk*64 + ch*4] = v;
    }
    __syncthreads();
    const int nn = tid>>2, kc = tid&3;
    u32t pk[8];
    if (mat == 3){
      #pragma unroll
      for (int p=0;p<8;p++){
        int q0 = kc*16 + 2*p, q1 = q0+1;
        int s0 = (q0 & 32) + ((q0&31)>>1) + ((q0&1)<<4);
        int s1 = (q1 & 32) + ((q1&31)>>1) + ((q1&1)<<4);
        pk[p] = (u32t)f2bf(Tf[s0*64+nn]) | ((u32t)f2bf(Tf[s1*64+nn])<<16);
      }
    } else {
      #pragma unroll
      for (int p=0;p<8;p++){
        float a  = Tf[(kc*16+2*p  )*64 + nn]*scale;
        float b2 = Tf[(kc*16+2*p+1)*64 + nn]*scale;
        pk[p] = (u32t)f2bf(a) | ((u32t)f2bf(b2)<<16);
      }
    }
    u16t* o = Wtb + ((size_t)mat*256 + nc0 + nn)*256 + k0 + kc*16;
    *(uint4*)o     = make_uint4(pk[0],pk[1],pk[2],pk[3]);
    *(uint4*)(o+8) = make_uint4(pk[4],pk[5],pk[6],pk[7]);
  } else if (b == 64){
    #pragma unroll
    for (int i=0;i<3;i++){
      int j = i*256 + tid;
      bb[j] = (j<256) ? bq[j]*QS : ((j<512) ? bk[j-256] : bv[j-512]);
    }
  } else if (b < 193){
    const int bi = b-65;
    #pragma unroll
    for (int i=0;i<8;i++){
      int idx = (bi*256+tid) + i*32768;   // float4 chunks, 262144 total
      float4 v = *(const float4*)(x + (size_t)idx*4);
      u32t p0 = (u32t)f2bf(v.x) | ((u32t)f2bf(v.y)<<16);
      u32t p1 = (u32t)f2bf(v.z) | ((u32t)f2bf(v.w)<<16);
      *(uint2*)(xb + (size_t)idx*4) = make_uint2(p0,p1);
    }
  } else {
    int e = (b-193)*256 + tid;
    int s = ei[e];
    int d = ei[NE + e];
    atomicOr(&A[(size_t)s*ROWW + (d>>6)], 1ull<<(d&63));
    atomicOr(&A[(size_t)d*ROWW + (s>>6)], 1ull<<(s&63));
    if (e < NN) atomicOr(&A[(size_t)e*ROWW + (e>>6)], 1ull<<(e&63));
  }
}

// ---------------- K1: QKV GEMM (64M x 128N, +direct V^T store) fused with reach-2 ----------------
__global__ __launch_bounds__(256) void k1_kernel(
    const u16t* __restrict__ xb, const u16t* __restrict__ Wtb,
    const float* __restrict__ bb, u16t* __restrict__ QKV, u16t* __restrict__ Vth,
    const u64t* __restrict__ A, u64t* __restrict__ MT)
{
  __shared__ __align__(16) u16t Xs[64*256];    // 32KB; reach2 + epilogue alias into it
  __shared__ int cnt;
  const int bx = blockIdx.x, tid = threadIdx.x;
  if (bx >= 384){
    const int n = bx - 384;
    u16t* list = Xs;                       // [0..8KB)
    u64t* accs = (u64t*)(Xs + 8192);       // [16KB..18KB)
    const int t = tid & 63;
    const int g = tid >> 6;
    if (tid==0) cnt=0;
    __syncthreads();
    if (tid < ROWW){
      u64t w = A[(size_t)n*ROWW + tid];
      int base = tid*64;
      while (w){
        int b = __builtin_ctzll(w);
        w &= w-1;
        int i = atomicAdd(&cnt,1);
        list[i] = (u16t)(base+b);
      }
    }
    __syncthreads();
    const int c = cnt;
    u64t acc = 0;
    int i = g;
    for (; i+12 < c; i += 16){
      u64t a0 = A[(size_t)list[i   ]*ROWW + t];
      u64t a1 = A[(size_t)list[i+4 ]*ROWW + t];
      u64t a2 = A[(size_t)list[i+8 ]*ROWW + t];
      u64t a3 = A[(size_t)list[i+12]*ROWW + t];
      acc |= a0 | a1 | a2 | a3;
    }
    for (; i < c; i += 4){
      acc |= A[(size_t)list[i]*ROWW + t];
    }
    accs[tid] = acc;
    __syncthreads();
    if (tid < ROWW){
      u64t a = accs[tid] | accs[64+tid] | accs[128+tid] | accs[192+tid];
      MT[(size_t)tid*NN + n] = a;          // transposed: word-major
    }
    return;
  }
  const int w = tid>>6, lane = tid&63, l15 = lane&15, quad = lane>>4;
  const int mt = bx / 6;
  const int nt = bx % 6;
  const int m0 = mt*64, n0 = nt*128;
  #pragma unroll
  for (int i=0;i<8;i++){
    int c = i*256 + tid;
    int row = c>>5, pc = c&31;
    int lc = pc ^ (row&7);
    gl2lds16(xb + (size_t)(m0+row)*256 + lc*8, &Xs[(size_t)(i*256 + w*64)*8]);
  }
  __syncthreads();
  bf16x8 afr[8];
  {
    const int row = w*16 + l15;
    #pragma unroll
    for (int kc=0;kc<8;kc++){
      const int phys = (kc*4+quad) ^ (row&7);
      uint4 t = *(const uint4*)&Xs[row*256 + phys*8];
      __builtin_memcpy(&afr[kc], &t, 16);
    }
  }
  f32x4 acc[8];
  #pragma unroll
  for (int nf=0;nf<8;nf++){
    float b2 = bb[n0 + nf*16 + l15];
    acc[nf] = (f32x4){b2,b2,b2,b2};
  }
  #pragma unroll
  for (int nf=0;nf<8;nf++){
    const u16t* Bp = Wtb + (size_t)(n0 + nf*16 + l15)*256 + quad*8;
    #pragma unroll
    for (int kc=0;kc<8;kc++){
      uint4 t = *(const uint4*)(Bp + kc*32);
      bf16x8 bfr; __builtin_memcpy(&bfr,&t,16);
      acc[nf] = __builtin_amdgcn_mfma_f32_16x16x32_bf16(afr[kc], bfr, acc[nf], 0,0,0);
    }
  }
  if (nt < 4){
    // LDS transpose -> coalesced row stores (Cs = 64 x 128 u16 = 16KB, aliases Xs)
    __syncthreads();
    u16t* Cs = Xs;
    #pragma unroll
    for (int nf=0;nf<8;nf++){
      const int col = nf*16 + l15;
      #pragma unroll
      for (int r=0;r<4;r++){
        Cs[(w*16+quad*4+r)*128 + col] = f2bf(acc[nf][r]);
      }
    }
    __syncthreads();
    #pragma unroll
    for (int i=0;i<4;i++){
      int id = i*256 + tid;
      int m = id>>4, c = id&15;
      uint4 v = *(const uint4*)&Cs[m*128 + c*8];
      *(uint4*)(QKV + (size_t)(m0+m)*512 + n0 + c*8) = v;
    }
  } else {
    // V^T: pack 4 consecutive m into one 8B store
    #pragma unroll
    for (int nf=0;nf<8;nf++){
      const int vcol = n0 - 512 + nf*16 + l15;   // 0..255 = h*32+d
      u32t a  = (u32t)f2bf(acc[nf][0]) | ((u32t)f2bf(acc[nf][1])<<16);
      u32t b2 = (u32t)f2bf(acc[nf][2]) | ((u32t)f2bf(acc[nf][3])<<16);
      *(uint2*)(Vth + (size_t)vcol*NN + m0 + w*16 + quad*4) = make_uint2(a,b2);
    }
  }
}

// ---------------- K2: flash attention, S^T + O^T in-register P^T, key-split x4 ----------------
// grid 1024: h = bx&7, qt = (bx>>3)&31 (128 q-rows), quarter = bx>>8 (0..3); 16 k-tiles each.
// O^T via mfma(V^T-frag, P^T-frag): P^T's B-layout == S^T's C-layout (k-index bijection).
__global__ __launch_bounds__(256) void fattn_kernel(
    const u64t* __restrict__ MT, const u16t* __restrict__ QKV,
    const u16t* __restrict__ Vth,
    u32t* __restrict__ attB, float* __restrict__ Lp)
{
  __shared__ __align__(16) u16t Ks[2][64*HDIM];
  __shared__ __align__(16) u16t Vs[2][HDIM*64];
  __shared__ __align__(16) u64t Ms[2][128];

  const int tid  = threadIdx.x;
  const int w    = tid >> 6;
  const int lane = tid & 63;
  const int l15  = lane & 15;
  const int quad = lane >> 4;
  const int h    = blockIdx.x & 7;
  const int n0   = ((blockIdx.x >> 3) & 31) * 128;
  const int quarter = blockIdx.x >> 8;
  const int kb   = quarter*16;
  const int ke   = kb+16;

  const u16t* Kg = QKV + 256 + h*HDIM;          // row-major stride 512
  const u16t* Vg = Vth + (size_t)h*HDIM*NN;
  const int kr = tid>>2, kqp = tid&3;
  const int kgo = kr*512 + (kqp ^ ((kr>>1)&3))*8;
  const int vr = tid>>3, vqp = tid&7;
  const int vgo = vr*NN + (vqp ^ (vr&7))*8;

  // Q B-operand frags for the two 64-row subtiles
  bf16x8 qf[2];
  #pragma unroll
  for (int s=0;s<2;s++){
    const u16t* qp = QKV + (size_t)(n0 + s*64 + w*16 + l15)*512 + h*HDIM + quad*8;
    uint4 t = *(const uint4*)qp;
    __builtin_memcpy(&qf[s], &t, 16);
  }
  bf16x8 ones8;
  {
    const short o = (short)0x3f80;      // bf16 1.0
    ones8 = (bf16x8){o,o,o,o,o,o,o,o};
  }

  // Oacc[s][dh] holds O^T: row d = dh*16 + quad*4 + r, col q = l15
  f32x4 Oacc[2][2] = {{{0.f,0.f,0.f,0.f},{0.f,0.f,0.f,0.f}},
                      {{0.f,0.f,0.f,0.f},{0.f,0.f,0.f,0.f}}};
  f32x4 Lacc[2]    = {{0.f,0.f,0.f,0.f},{0.f,0.f,0.f,0.f}};
  const f32x4 zero = {0.f,0.f,0.f,0.f};

  #define STAGE(kt, buf) do { \
    gl2lds16(Kg + (size_t)(kt)*64*512 + kgo, &Ks[(buf)][w*512]); \
    gl2lds16(Vg + (size_t)(kt)*64 + vgo,  &Vs[(buf)][w*512]); \
    if (tid < 64) gl2lds16(MT + (size_t)(kt)*NN + n0 + tid*2, &Ms[(buf)][0]); \
  } while(0)

  STAGE(kb, kb&1);
  const int kswz = (l15>>1)&3;

  for (int kt=kb; kt<ke; ++kt){
    __syncthreads();
    if (kt+1 < ke) STAGE(kt+1, (kt+1)&1);
    const int buf = kt&1;

    // V^T A-operand frags (shared by both subtiles): pair gp covers groups 2gp,2gp+1
    bf16x8 vf[2][2];
    #pragma unroll
    for (int gp=0; gp<2; ++gp){
      #pragma unroll
      for (int dh=0; dh<2; ++dh){
        const int row = dh*16 + l15;
        const int half = (quad&1)*4;
        const u16t* v0 = &Vs[buf][row*64 + (((gp*4   + (quad>>1)) ^ (l15&7))<<3) + half];
        const u16t* v1 = &Vs[buf][row*64 + (((gp*4+2 + (quad>>1)) ^ (l15&7))<<3) + half];
        uint2 a = *(const uint2*)v0;
        uint2 b = *(const uint2*)v1;
        uint4 t = make_uint4(a.x, a.y, b.x, b.y);
        __builtin_memcpy(&vf[gp][dh], &t, 16);
      }
    }

    // per subtile: S^T, mask+exp, pack -> P^T B-frag, MFMA into O^T and L
    #pragma unroll
    for (int s=0;s<2;s++){
      f32x4 S[4];
      #pragma unroll
      for (int g=0; g<4; ++g){
        const u16t* kp = &Ks[buf][(g*16+l15)*HDIM + (quad ^ kswz)*8];
        uint4 t = *(const uint4*)kp;
        bf16x8 kf; __builtin_memcpy(&kf,&t,16);
        S[g] = __builtin_amdgcn_mfma_f32_16x16x32_bf16(kf, qf[s], zero, 0,0,0);
      }
      u64t mw = Ms[buf][s*64 + w*16 + l15] >> (quad*4);
      u32t slo = (u32t)mw, shi = (u32t)(mw>>32);
      #pragma unroll
      for (int g=0; g<4; ++g){
        const u32t sv = (g&2)? shi : slo;
        const int base = (g&1)*16;
        #pragma unroll
        for (int r=0;r<4;r++){
          float p = fexp2(S[g][r]);
          u32t pi; __builtin_memcpy(&pi,&p,4);
          pi &= (u32t)sbfe1(sv, base+r);
          __builtin_memcpy(&p,&pi,4);
          S[g][r] = p;
        }
      }
      #pragma unroll
      for (int gp=0; gp<2; ++gp){
        uint4 tb = make_uint4(pk2t(S[2*gp][0],  S[2*gp][1]),
                              pk2t(S[2*gp][2],  S[2*gp][3]),
                              pk2t(S[2*gp+1][0],S[2*gp+1][1]),
                              pk2t(S[2*gp+1][2],S[2*gp+1][3]));
        bf16x8 pb; __builtin_memcpy(&pb,&tb,16);
        Lacc[s]    = __builtin_amdgcn_mfma_f32_16x16x32_bf16(ones8,    pb, Lacc[s],    0,0,0);
        Oacc[s][0] = __builtin_amdgcn_mfma_f32_16x16x32_bf16(vf[gp][0], pb, Oacc[s][0], 0,0,0);
        Oacc[s][1] = __builtin_amdgcn_mfma_f32_16x16x32_bf16(vf[gp][1], pb, Oacc[s][1], 0,0,0);
      }
    }
  }
  #undef STAGE

  // epilogue: O^T -> coalesced uint4 stores; L[q] identical across regs
  #pragma unroll
  for (int s=0;s<2;s++){
    const int n = n0 + s*64 + w*16 + l15;
    if (quad == 0)
      Lp[(size_t)quarter*NH*NN + (size_t)h*NN + n] = Lacc[s][0];
    uint4 o;
    o.x = (u32t)f2bf(Oacc[s][0][0]) | ((u32t)f2bf(Oacc[s][1][0])<<16);
    o.y = (u32t)f2bf(Oacc[s][0][1]) | ((u32t)f2bf(Oacc[s][1][1])<<16);
    o.z = (u32t)f2bf(Oacc[s][0][2]) | ((u32t)f2bf(Oacc[s][1][2])<<16);
    o.w = (u32t)f2bf(Oacc[s][0][3]) | ((u32t)f2bf(Oacc[s][1][3])<<16);
    *(uint4*)&attB[((size_t)quarter*NN + n)*128 + h*16 + quad*4] = o;
  }
}

// ---------------- K3: merge 4 partials + out-proj (MFMA, permuted WoT) + residual + layernorm ----------------
__global__ __launch_bounds__(256) void outln_kernel(
    const u32t* __restrict__ attB, const float* __restrict__ Lp,
    const u16t* __restrict__ WoT, const float* __restrict__ bo,
    const float* __restrict__ x, const float* __restrict__ lnw, const float* __restrict__ lnb,
    float* __restrict__ out)
{
  __shared__ __align__(16) u16t As[16*256];
  __shared__ float Lr[8*16];
  __shared__ float red1[16][4], red2[16][4];
  const int tid = threadIdx.x;
  const int w = tid>>6, lane = tid&63, l15 = lane&15, quad = lane>>4;
  const int n0 = blockIdx.x*16;

  if (tid < 128){
    int hh = tid>>4, rr = tid&15;
    float l = Lp[(size_t)hh*NN + n0+rr]
            + Lp[(size_t)NH*NN + (size_t)hh*NN + n0+rr]
            + Lp[(size_t)2*NH*NN + (size_t)hh*NN + n0+rr]
            + Lp[(size_t)3*NH*NN + (size_t)hh*NN + n0+rr];
    Lr[tid] = 1.f/l;
  }
  __syncthreads();
  // merge 4 bf16-paired partials -> normalized bf16 As (permuted col order, swizzled)
  #pragma unroll
  for (int it=0; it<8; ++it){
    int e = it*256 + tid;           // 2048 = 16 rows x 128 u32
    int n = e>>7, j = e&127;
    float s0=0.f, s1=0.f;
    #pragma unroll
    for (int qq=0;qq<4;qq++){
      u32t u = attB[((size_t)qq*NN + n0+n)*128 + j];
      u32t ul = u<<16, uh = u & 0xffff0000u;
      float lo, hi;
      __builtin_memcpy(&lo,&ul,4); __builtin_memcpy(&hi,&uh,4);
      s0 += lo; s1 += hi;
    }
    float rinv = Lr[(j>>4)*16 + n];
    u32t pkd = pk2t(s0*rinv, s1*rinv);
    ((u32t*)As)[n*128 + ((j>>2) ^ (n&7))*4 + (j&3)] = pkd;
  }
  __syncthreads();

  bf16x8 afr[8];
  #pragma unroll
  for (int kc=0;kc<8;kc++){
    const int phys = (kc*4+quad) ^ (l15&7);
    uint4 t = *(const uint4*)&As[l15*256 + phys*8];
    __builtin_memcpy(&afr[kc], &t, 16);
  }
  f32x4 acc[4];
  #pragma unroll
  for (int nf=0;nf<4;nf++){
    const int col = w*64 + nf*16 + l15;
    float b2 = bo[col];
    acc[nf] = (f32x4){b2,b2,b2,b2};
    const u16t* Bp = WoT + (size_t)col*256 + quad*8;
    #pragma unroll
    for (int kc=0;kc<8;kc++){
      uint4 t = *(const uint4*)(Bp + kc*32);
      bf16x8 bfr; __builtin_memcpy(&bfr,&t,16);
      acc[nf] = __builtin_amdgcn_mfma_f32_16x16x32_bf16(afr[kc], bfr, acc[nf], 0,0,0);
    }
  }
  float ps1[4]={0,0,0,0}, ps2[4]={0,0,0,0};
  #pragma unroll
  for (int nf=0;nf<4;nf++){
    const int col = w*64 + nf*16 + l15;
    #pragma unroll
    for (int r=0;r<4;r++){
      float v = acc[nf][r] + x[(size_t)(n0+quad*4+r)*DM + col];
      acc[nf][r] = v;
      ps1[r] += v;
      ps2[r] += v*v;
    }
  }
  #pragma unroll
  for (int r=0;r<4;r++){
    ps1[r] += __shfl_xor(ps1[r],1); ps2[r] += __shfl_xor(ps2[r],1);
    ps1[r] += __shfl_xor(ps1[r],2); ps2[r] += __shfl_xor(ps2[r],2);
    ps1[r] += __shfl_xor(ps1[r],4); ps2[r] += __shfl_xor(ps2[r],4);
    ps1[r] += __shfl_xor(ps1[r],8); ps2[r] += __shfl_xor(ps2[r],8);
    if (l15==0){ red1[quad*4+r][w]=ps1[r]; red2[quad*4+r][w]=ps2[r]; }
  }
  __syncthreads();
  float mu[4], rs[4];
  #pragma unroll
  for (int r=0;r<4;r++){
    const int row = quad*4+r;
    float s1 = red1[row][0]+red1[row][1]+red1[row][2]+red1[row][3];
    float s2 = red2[row][0]+red2[row][1]+red2[row][2]+red2[row][3];
    mu[r] = s1*(1.0f/256.0f);
    float var = s2*(1.0f/256.0f) - mu[r]*mu[r];
    rs[r] = rsqrtf(var+1e-5f);
  }
  #pragma unroll
  for (int nf=0;nf<4;nf++){
    const int col = w*64 + nf*16 + l15;
    const float lw = lnw[col], lb = lnb[col];
    #pragma unroll
    for (int r=0;r<4;r++){
      out[(size_t)(n0+quad*4+r)*DM + col] = (acc[nf][r]-mu[r])*rs[r]*lw + lb;
    }
  }
}

extern "C" void kernel_launch(void* const* d_in, const int* in_sizes, int n_in,
                              void* d_out, int out_size, void* d_ws, size_t ws_size,
                              hipStream_t stream) {
  const float* x   = (const float*)d_in[0];
  const int*   ei  = (const int*  )d_in[1];
  const float* Wq  = (const float*)d_in[2];
  const float* bq  = (const float*)d_in[3];
  const float* Wk  = (const float*)d_in[4];
  const float* bk  = (const float*)d_in[5];
  const float* Wv  = (const float*)d_in[6];
  const float* bv  = (const float*)d_in[7];
  const float* Wo  = (const float*)d_in[8];
  const float* bo  = (const float*)d_in[9];
  const float* lnw = (const float*)d_in[10];
  const float* lnb = (const float*)d_in[11];

  char* ws = (char*)d_ws;
  u64t*  A    = (u64t*)(ws);                     // 0..2MB adjacency bits (memset)
  u64t*  MT   = (u64t*)(ws + (2u<<20));          // 2..4MB reach-2 bits, transposed [64][4096]
  u32t*  attB = (u32t*)(ws + (4u<<20));          // 4..12MB O^T partials [4][4096][128] u32 (bf16 pairs)
  u16t*  xb   = (u16t*)(ws + (4u<<20));          // alias attB[0..2MB): conv->gemm only
  u16t*  QKV  = (u16t*)(ws + (12u<<20));         // 12..16MB [4096][512] bf16 (Q|K)
  u16t*  Vth  = (u16t*)(ws + (16u<<20));         // 16..18MB [256][4096] bf16 V^T
  float* Lp   = (float*)(ws + (18u<<20));        // 18..18.5MB L partials [4][8][4096]
  u16t*  Wtb  = (u16t*)(ws + (19u<<20));         // 19..19.5MB W^T bf16 (4 mats)
  float* bb   = (float*)(ws + (19u<<20) + (512u<<10)); // bias fp32 (768)

  hipMemsetAsync(A, 0, (2u<<20), stream);
  k0_kernel  <<<449,  256, 0, stream>>>(Wq,bq, Wk,bk, Wv,bv, Wo, x, Wtb, bb, xb, ei, A);
  k1_kernel  <<<4480, 256, 0, stream>>>(xb, Wtb, bb, QKV, Vth, A, MT);
  fattn_kernel<<<1024, 256, 0, stream>>>(MT, QKV, Vth, attB, Lp);
  outln_kernel<<<256,  256, 0, stream>>>(attB, Lp, Wtb + (size_t)3*256*256, bo, x, lnw, lnb, (float*)d_out);
}

// Round 14
// 153.698 us; speedup vs baseline: 1.0230x; 1.0160x over previous
//
#include <hip/hip_runtime.h>
#include <math.h>

#define NN   4096
#define DM   256
#define NH   8
#define HDIM 32
#define NE   65536
#define ROWW 64
#define QS   0.25503473f   // log2(e)/sqrt(32)

typedef unsigned short u16t;
typedef unsigned int   u32t;
typedef unsigned long long u64t;
typedef __attribute__((ext_vector_type(8))) short bf16x8;
typedef __attribute__((ext_vector_type(4))) float f32x4;

__device__ __forceinline__ u16t f2bf(float f){            // RNE
  u32t x; __builtin_memcpy(&x,&f,4);
  u32t r=(x+0x7fffu+((x>>16)&1u))>>16;
  return (u16t)r;
}
__device__ __forceinline__ float fexp2(float x){
#if __has_builtin(__builtin_amdgcn_exp2f)
  return __builtin_amdgcn_exp2f(x);
#else
  return exp2f(x);
#endif
}
__device__ __forceinline__ int sbfe1(u32t v, int pos){    // 0 or -1 from bit
#if __has_builtin(__builtin_amdgcn_sbfe)
  return __builtin_amdgcn_sbfe((int)v, pos, 1);
#else
  return ((int)(v << (31-pos))) >> 31;
#endif
}
// truncating bf16 pair pack: lo16 = hi16(a), hi16 = hi16(b)
__device__ __forceinline__ u32t pk2t(float a, float b){
  u32t xa, xb;
  __builtin_memcpy(&xa,&a,4); __builtin_memcpy(&xb,&b,4);
#if __has_builtin(__builtin_amdgcn_perm)
  return __builtin_amdgcn_perm(xb, xa, 0x07060302u);
#else
  return (xa>>16) | (xb & 0xffff0000u);
#endif
}
__device__ __forceinline__ void gl2lds16(const void* g, void* l){
  auto gp = (const __attribute__((address_space(1))) u32t*)(unsigned long long)g;
  auto lp = (__attribute__((address_space(3))) u32t*)(u32t)(unsigned long long)l;
  __builtin_amdgcn_global_load_lds(gp, lp, 16, 0, 0);
}

// ---------------- K0: W transposes + bias + x->bf16 + edge bitmask ----------------
// Wo gets its k-rows PERMUTED: stored p=h*32+2i <- orig h*32+i ; p=h*32+2i+1 <- orig h*32+16+i
__global__ __launch_bounds__(256) void k0_kernel(
    const float* __restrict__ Wq, const float* __restrict__ bq,
    const float* __restrict__ Wk, const float* __restrict__ bk,
    const float* __restrict__ Wv, const float* __restrict__ bv,
    const float* __restrict__ Wo, const float* __restrict__ x,
    u16t* __restrict__ Wtb, float* __restrict__ bb, u16t* __restrict__ xb,
    const int* __restrict__ ei, u64t* __restrict__ A)
{
  const int b = blockIdx.x, tid = threadIdx.x;
  if (b < 64){
    __shared__ __align__(16) float Tf[64*64];
    const int mat = b>>4, t = b&15;
    const int k0 = (t>>2)*64, nc0 = (t&3)*64;
    const float* W = mat==0? Wq : (mat==1? Wk : (mat==2? Wv : Wo));
    const float scale = (mat==0) ? QS : 1.0f;
    #pragma unroll
    for (int i=0;i<4;i++){
      int c = i*256+tid;
      int kk = c>>4, ch = c&15;
      float4 v = *(const float4*)(W + (size_t)(k0+kk)*256 + nc0 + ch*4);
      *(float4*)&Tf[kk*64 + ch*4] = v;
    }
    __syncthreads();
    const int nn = tid>>2, kc = tid&3;
    u32t pk[8];
    if (mat == 3){
      #pragma unroll
      for (int p=0;p<8;p++){
        int q0 = kc*16 + 2*p, q1 = q0+1;
        int s0 = (q0 & 32) + ((q0&31)>>1) + ((q0&1)<<4);
        int s1 = (q1 & 32) + ((q1&31)>>1) + ((q1&1)<<4);
        pk[p] = (u32t)f2bf(Tf[s0*64+nn]) | ((u32t)f2bf(Tf[s1*64+nn])<<16);
      }
    } else {
      #pragma unroll
      for (int p=0;p<8;p++){
        float a  = Tf[(kc*16+2*p  )*64 + nn]*scale;
        float b2 = Tf[(kc*16+2*p+1)*64 + nn]*scale;
        pk[p] = (u32t)f2bf(a) | ((u32t)f2bf(b2)<<16);
      }
    }
    u16t* o = Wtb + ((size_t)mat*256 + nc0 + nn)*256 + k0 + kc*16;
    *(uint4*)o     = make_uint4(pk[0],pk[1],pk[2],pk[3]);
    *(uint4*)(o+8) = make_uint4(pk[4],pk[5],pk[6],pk[7]);
  } else if (b == 64){
    #pragma unroll
    for (int i=0;i<3;i++){
      int j = i*256 + tid;
      bb[j] = (j<256) ? bq[j]*QS : ((j<512) ? bk[j-256] : bv[j-512]);
    }
  } else if (b < 193){
    const int bi = b-65;
    #pragma unroll
    for (int i=0;i<8;i++){
      int idx = (bi*256+tid) + i*32768;   // float4 chunks, 262144 total
      float4 v = *(const float4*)(x + (size_t)idx*4);
      u32t p0 = (u32t)f2bf(v.x) | ((u32t)f2bf(v.y)<<16);
      u32t p1 = (u32t)f2bf(v.z) | ((u32t)f2bf(v.w)<<16);
      *(uint2*)(xb + (size_t)idx*4) = make_uint2(p0,p1);
    }
  } else {
    int e = (b-193)*256 + tid;
    int s = ei[e];
    int d = ei[NE + e];
    atomicOr(&A[(size_t)s*ROWW + (d>>6)], 1ull<<(d&63));
    atomicOr(&A[(size_t)d*ROWW + (s>>6)], 1ull<<(s&63));
    if (e < NN) atomicOr(&A[(size_t)e*ROWW + (e>>6)], 1ull<<(e&63));
  }
}

// ---------------- K1: QKV GEMM (64M x 128N, +direct V^T store) fused with reach-2 ----------------
__global__ __launch_bounds__(256) void k1_kernel(
    const u16t* __restrict__ xb, const u16t* __restrict__ Wtb,
    const float* __restrict__ bb, u16t* __restrict__ QKV, u16t* __restrict__ Vth,
    const u64t* __restrict__ A, u64t* __restrict__ MT)
{
  __shared__ __align__(16) u16t Xs[64*256];    // 32KB; reach2 + epilogue alias into it
  __shared__ int cnt;
  const int bx = blockIdx.x, tid = threadIdx.x;
  if (bx >= 384){
    const int n = bx - 384;
    u16t* list = Xs;                       // [0..8KB)
    u64t* accs = (u64t*)(Xs + 8192);       // [16KB..18KB)
    const int t = tid & 63;
    const int g = tid >> 6;
    if (tid==0) cnt=0;
    __syncthreads();
    if (tid < ROWW){
      u64t w = A[(size_t)n*ROWW + tid];
      int base = tid*64;
      while (w){
        int b = __builtin_ctzll(w);
        w &= w-1;
        int i = atomicAdd(&cnt,1);
        list[i] = (u16t)(base+b);
      }
    }
    __syncthreads();
    const int c = cnt;
    u64t acc = 0;
    int i = g;
    for (; i+12 < c; i += 16){
      u64t a0 = A[(size_t)list[i   ]*ROWW + t];
      u64t a1 = A[(size_t)list[i+4 ]*ROWW + t];
      u64t a2 = A[(size_t)list[i+8 ]*ROWW + t];
      u64t a3 = A[(size_t)list[i+12]*ROWW + t];
      acc |= a0 | a1 | a2 | a3;
    }
    for (; i < c; i += 4){
      acc |= A[(size_t)list[i]*ROWW + t];
    }
    accs[tid] = acc;
    __syncthreads();
    if (tid < ROWW){
      u64t a = accs[tid] | accs[64+tid] | accs[128+tid] | accs[192+tid];
      MT[(size_t)tid*NN + n] = a;          // transposed: word-major
    }
    return;
  }
  const int w = tid>>6, lane = tid&63, l15 = lane&15, quad = lane>>4;
  const int mt = bx / 6;
  const int nt = bx % 6;
  const int m0 = mt*64, n0 = nt*128;
  #pragma unroll
  for (int i=0;i<8;i++){
    int c = i*256 + tid;
    int row = c>>5, pc = c&31;
    int lc = pc ^ (row&7);
    gl2lds16(xb + (size_t)(m0+row)*256 + lc*8, &Xs[(size_t)(i*256 + w*64)*8]);
  }
  __syncthreads();
  bf16x8 afr[8];
  {
    const int row = w*16 + l15;
    #pragma unroll
    for (int kc=0;kc<8;kc++){
      const int phys = (kc*4+quad) ^ (row&7);
      uint4 t = *(const uint4*)&Xs[row*256 + phys*8];
      __builtin_memcpy(&afr[kc], &t, 16);
    }
  }
  f32x4 acc[8];
  #pragma unroll
  for (int nf=0;nf<8;nf++){
    float b2 = bb[n0 + nf*16 + l15];
    acc[nf] = (f32x4){b2,b2,b2,b2};
  }
  #pragma unroll
  for (int nf=0;nf<8;nf++){
    const u16t* Bp = Wtb + (size_t)(n0 + nf*16 + l15)*256 + quad*8;
    #pragma unroll
    for (int kc=0;kc<8;kc++){
      uint4 t = *(const uint4*)(Bp + kc*32);
      bf16x8 bfr; __builtin_memcpy(&bfr,&t,16);
      acc[nf] = __builtin_amdgcn_mfma_f32_16x16x32_bf16(afr[kc], bfr, acc[nf], 0,0,0);
    }
  }
  if (nt < 4){
    // LDS transpose -> coalesced row stores (Cs = 64 x 128 u16 = 16KB, aliases Xs)
    __syncthreads();
    u16t* Cs = Xs;
    #pragma unroll
    for (int nf=0;nf<8;nf++){
      const int col = nf*16 + l15;
      #pragma unroll
      for (int r=0;r<4;r++){
        Cs[(w*16+quad*4+r)*128 + col] = f2bf(acc[nf][r]);
      }
    }
    __syncthreads();
    #pragma unroll
    for (int i=0;i<4;i++){
      int id = i*256 + tid;
      int m = id>>4, c = id&15;
      uint4 v = *(const uint4*)&Cs[m*128 + c*8];
      *(uint4*)(QKV + (size_t)(m0+m)*512 + n0 + c*8) = v;
    }
  } else {
    // V^T: pack 4 consecutive m into one 8B store
    #pragma unroll
    for (int nf=0;nf<8;nf++){
      const int vcol = n0 - 512 + nf*16 + l15;   // 0..255 = h*32+d
      u32t a  = (u32t)f2bf(acc[nf][0]) | ((u32t)f2bf(acc[nf][1])<<16);
      u32t b2 = (u32t)f2bf(acc[nf][2]) | ((u32t)f2bf(acc[nf][3])<<16);
      *(uint2*)(Vth + (size_t)vcol*NN + m0 + w*16 + quad*4) = make_uint2(a,b2);
    }
  }
}

// ---------------- K2: flash attention, S^T scheme, 128 q-rows/block, key-split x4 ----------------
// grid 1024: h = bx&7, qt = (bx>>3)&31, quarter = bx>>8 (0..3); 16 k-tiles each.
// O partials stored bf16-paired: attB u32 [4][4096][128], entry h*16+l15 = (d=l15 | d=16+l15<<16)
__global__ __launch_bounds__(256) void fattn_kernel(
    const u64t* __restrict__ MT, const u16t* __restrict__ QKV,
    const u16t* __restrict__ Vth,
    u32t* __restrict__ attB, float* __restrict__ Lp)
{
  __shared__ __align__(16) u16t Ks[2][64*HDIM];
  __shared__ __align__(16) u16t Vs[2][HDIM*64];
  __shared__ __align__(16) u64t Ms[2][128];
  __shared__ __align__(16) u16t Ps[4][2][16*64];

  const int tid  = threadIdx.x;
  const int w    = tid >> 6;
  const int lane = tid & 63;
  const int l15  = lane & 15;
  const int quad = lane >> 4;
  const int h    = blockIdx.x & 7;
  const int n0   = ((blockIdx.x >> 3) & 31) * 128;
  const int quarter = blockIdx.x >> 8;
  const int kb   = quarter*16;
  const int ke   = kb+16;

  const u16t* Kg = QKV + 256 + h*HDIM;          // row-major stride 512
  const u16t* Vg = Vth + (size_t)h*HDIM*NN;
  const int kr = tid>>2, kqp = tid&3;
  const int kgo = kr*512 + (kqp ^ ((kr>>1)&3))*8;
  const int vr = tid>>3, vqp = tid&7;
  const int vgo = vr*NN + (vqp ^ (vr&7))*8;

  // Q B-operand frags for the two 64-row subtiles
  bf16x8 qf[2];
  #pragma unroll
  for (int s=0;s<2;s++){
    const u16t* qp = QKV + (size_t)(n0 + s*64 + w*16 + l15)*512 + h*HDIM + quad*8;
    uint4 t = *(const uint4*)qp;
    __builtin_memcpy(&qf[s], &t, 16);
  }
  bf16x8 ones8;
  {
    const short o = (short)0x3f80;      // bf16 1.0
    ones8 = (bf16x8){o,o,o,o,o,o,o,o};
  }

  f32x4 Oacc[2][2] = {{{0.f,0.f,0.f,0.f},{0.f,0.f,0.f,0.f}},
                      {{0.f,0.f,0.f,0.f},{0.f,0.f,0.f,0.f}}};
  f32x4 Lacc[2]    = {{0.f,0.f,0.f,0.f},{0.f,0.f,0.f,0.f}};
  const f32x4 zero = {0.f,0.f,0.f,0.f};

  #define STAGE(kt, buf) do { \
    gl2lds16(Kg + (size_t)(kt)*64*512 + kgo, &Ks[(buf)][w*512]); \
    gl2lds16(Vg + (size_t)(kt)*64 + vgo,  &Vs[(buf)][w*512]); \
    if (tid < 64) gl2lds16(MT + (size_t)(kt)*NN + n0 + tid*2, &Ms[(buf)][0]); \
  } while(0)

  STAGE(kb, kb&1);
  const int kswz = (l15>>1)&3;
  const int pswz = l15&7;
  const int e2   = (l15&7)<<1;          // 4-u16-chunk swizzle for Ps

  for (int kt=kb; kt<ke; ++kt){
    __syncthreads();
    if (kt+1 < ke) STAGE(kt+1, (kt+1)&1);
    const int buf = kt&1;

    // K A-operand frags (shared by both subtiles)
    bf16x8 kf[4];
    #pragma unroll
    for (int g=0; g<4; ++g){
      const u16t* kp = &Ks[buf][(g*16+l15)*HDIM + (quad ^ kswz)*8];
      uint4 t = *(const uint4*)kp;
      __builtin_memcpy(&kf[g], &t, 16);
    }

    // S^T + mask + exp + pack, per subtile
    #pragma unroll
    for (int s=0;s<2;s++){
      f32x4 S[4];
      #pragma unroll
      for (int g=0; g<4; ++g)
        S[g] = __builtin_amdgcn_mfma_f32_16x16x32_bf16(kf[g], qf[s], zero, 0,0,0);
      u64t mw = Ms[buf][s*64 + w*16 + l15] >> (quad*4);
      u32t slo = (u32t)mw, shi = (u32t)(mw>>32);
      #pragma unroll
      for (int g=0; g<4; ++g){
        const u32t sv = (g&2)? shi : slo;
        const int base = (g&1)*16;
        #pragma unroll
        for (int r=0;r<4;r++){
          float p = fexp2(S[g][r]);
          u32t pi; __builtin_memcpy(&pi,&p,4);
          pi &= (u32t)sbfe1(sv, base+r);
          __builtin_memcpy(&p,&pi,4);
          S[g][r] = p;
        }
        u32t lo = pk2t(S[g][0], S[g][1]);
        u32t hi = pk2t(S[g][2], S[g][3]);
        *(uint2*)&Ps[w][s][l15*64 + (((g*4+quad) ^ e2)<<2)] = make_uint2(lo,hi);
      }
    }

    // O += P V ; L += P @ ones.  V frags read once, reused across subtiles.
    #pragma unroll
    for (int kc=0; kc<2; ++kc){
      bf16x8 pa[2];
      #pragma unroll
      for (int s=0;s<2;s++){
        const u16t* pp = &Ps[w][s][l15*64 + (((kc*8+quad*2) ^ e2)<<2)];
        uint4 ta = *(const uint4*)pp;
        __builtin_memcpy(&pa[s],&ta,16);
        Lacc[s] = __builtin_amdgcn_mfma_f32_16x16x32_bf16(pa[s], ones8, Lacc[s], 0,0,0);
      }
      #pragma unroll
      for (int dh=0; dh<2; ++dh){
        const u16t* vp = &Vs[buf][(dh*16+l15)*64 + ((kc*4+quad) ^ pswz)*8];
        uint4 tb = *(const uint4*)vp;
        bf16x8 vb; __builtin_memcpy(&vb,&tb,16);
        #pragma unroll
        for (int s=0;s<2;s++)
          Oacc[s][dh] = __builtin_amdgcn_mfma_f32_16x16x32_bf16(pa[s], vb, Oacc[s][dh], 0,0,0);
      }
    }
  }
  #undef STAGE

  // epilogue: bf16-paired O partials + L
  #pragma unroll
  for (int s=0;s<2;s++){
    if (l15 == 0){
      float4 lv = {Lacc[s][0], Lacc[s][1], Lacc[s][2], Lacc[s][3]};
      *(float4*)(Lp + (size_t)quarter*NH*NN + (size_t)h*NN + n0 + s*64 + w*16 + quad*4) = lv;
    }
    #pragma unroll
    for (int r=0;r<4;r++){
      const int n = n0 + s*64 + w*16 + quad*4 + r;
      attB[((size_t)quarter*NN + n)*128 + h*16 + l15] =
        (u32t)f2bf(Oacc[s][0][r]) | ((u32t)f2bf(Oacc[s][1][r])<<16);
    }
  }
}

// ---------------- K3: merge 4 partials + out-proj (MFMA, permuted WoT) + residual + layernorm ----------------
__global__ __launch_bounds__(256) void outln_kernel(
    const u32t* __restrict__ attB, const float* __restrict__ Lp,
    const u16t* __restrict__ WoT, const float* __restrict__ bo,
    const float* __restrict__ x, const float* __restrict__ lnw, const float* __restrict__ lnb,
    float* __restrict__ out)
{
  __shared__ __align__(16) u16t As[16*256];
  __shared__ float Lr[8*16];
  __shared__ float red1[16][4], red2[16][4];
  const int tid = threadIdx.x;
  const int w = tid>>6, lane = tid&63, l15 = lane&15, quad = lane>>4;
  const int n0 = blockIdx.x*16;

  if (tid < 128){
    int hh = tid>>4, rr = tid&15;
    float l = Lp[(size_t)hh*NN + n0+rr]
            + Lp[(size_t)NH*NN + (size_t)hh*NN + n0+rr]
            + Lp[(size_t)2*NH*NN + (size_t)hh*NN + n0+rr]
            + Lp[(size_t)3*NH*NN + (size_t)hh*NN + n0+rr];
    Lr[tid] = 1.f/l;
  }
  __syncthreads();
  // merge 4 bf16-paired partials -> normalized bf16 As (permuted col order, swizzled)
  #pragma unroll
  for (int it=0; it<8; ++it){
    int e = it*256 + tid;           // 2048 = 16 rows x 128 u32
    int n = e>>7, j = e&127;
    float s0=0.f, s1=0.f;
    #pragma unroll
    for (int qq=0;qq<4;qq++){
      u32t u = attB[((size_t)qq*NN + n0+n)*128 + j];
      u32t ul = u<<16, uh = u & 0xffff0000u;
      float lo, hi;
      __builtin_memcpy(&lo,&ul,4); __builtin_memcpy(&hi,&uh,4);
      s0 += lo; s1 += hi;
    }
    float rinv = Lr[(j>>4)*16 + n];
    u32t pkd = pk2t(s0*rinv, s1*rinv);
    ((u32t*)As)[n*128 + ((j>>2) ^ (n&7))*4 + (j&3)] = pkd;
  }
  __syncthreads();

  bf16x8 afr[8];
  #pragma unroll
  for (int kc=0;kc<8;kc++){
    const int phys = (kc*4+quad) ^ (l15&7);
    uint4 t = *(const uint4*)&As[l15*256 + phys*8];
    __builtin_memcpy(&afr[kc], &t, 16);
  }
  f32x4 acc[4];
  #pragma unroll
  for (int nf=0;nf<4;nf++){
    const int col = w*64 + nf*16 + l15;
    float b2 = bo[col];
    acc[nf] = (f32x4){b2,b2,b2,b2};
    const u16t* Bp = WoT + (size_t)col*256 + quad*8;
    #pragma unroll
    for (int kc=0;kc<8;kc++){
      uint4 t = *(const uint4*)(Bp + kc*32);
      bf16x8 bfr; __builtin_memcpy(&bfr,&t,16);
      acc[nf] = __builtin_amdgcn_mfma_f32_16x16x32_bf16(afr[kc], bfr, acc[nf], 0,0,0);
    }
  }
  float ps1[4]={0,0,0,0}, ps2[4]={0,0,0,0};
  #pragma unroll
  for (int nf=0;nf<4;nf++){
    const int col = w*64 + nf*16 + l15;
    #pragma unroll
    for (int r=0;r<4;r++){
      float v = acc[nf][r] + x[(size_t)(n0+quad*4+r)*DM + col];
      acc[nf][r] = v;
      ps1[r] += v;
      ps2[r] += v*v;
    }
  }
  #pragma unroll
  for (int r=0;r<4;r++){
    ps1[r] += __shfl_xor(ps1[r],1); ps2[r] += __shfl_xor(ps2[r],1);
    ps1[r] += __shfl_xor(ps1[r],2); ps2[r] += __shfl_xor(ps2[r],2);
    ps1[r] += __shfl_xor(ps1[r],4); ps2[r] += __shfl_xor(ps2[r],4);
    ps1[r] += __shfl_xor(ps1[r],8); ps2[r] += __shfl_xor(ps2[r],8);
    if (l15==0){ red1[quad*4+r][w]=ps1[r]; red2[quad*4+r][w]=ps2[r]; }
  }
  __syncthreads();
  float mu[4], rs[4];
  #pragma unroll
  for (int r=0;r<4;r++){
    const int row = quad*4+r;
    float s1 = red1[row][0]+red1[row][1]+red1[row][2]+red1[row][3];
    float s2 = red2[row][0]+red2[row][1]+red2[row][2]+red2[row][3];
    mu[r] = s1*(1.0f/256.0f);
    float var = s2*(1.0f/256.0f) - mu[r]*mu[r];
    rs[r] = rsqrtf(var+1e-5f);
  }
  #pragma unroll
  for (int nf=0;nf<4;nf++){
    const int col = w*64 + nf*16 + l15;
    const float lw = lnw[col], lb = lnb[col];
    #pragma unroll
    for (int r=0;r<4;r++){
      out[(size_t)(n0+quad*4+r)*DM + col] = (acc[nf][r]-mu[r])*rs[r]*lw + lb;
    }
  }
}

extern "C" void kernel_launch(void* const* d_in, const int* in_sizes, int n_in,
                              void* d_out, int out_size, void* d_ws, size_t ws_size,
                              hipStream_t stream) {
  const float* x   = (const float*)d_in[0];
  const int*   ei  = (const int*  )d_in[1];
  const float* Wq  = (const float*)d_in[2];
  const float* bq  = (const float*)d_in[3];
  const float* Wk  = (const float*)d_in[4];
  const float* bk  = (const float*)d_in[5];
  const float* Wv  = (const float*)d_in[6];
  const float* bv  = (const float*)d_in[7];
  const float* Wo  = (const float*)d_in[8];
  const float* bo  = (const float*)d_in[9];
  const float* lnw = (const float*)d_in[10];
  const float* lnb = (const float*)d_in[11];

  char* ws = (char*)d_ws;
  u64t*  A    = (u64t*)(ws);                     // 0..2MB adjacency bits (memset)
  u64t*  MT   = (u64t*)(ws + (2u<<20));          // 2..4MB reach-2 bits, transposed [64][4096]
  u32t*  attB = (u32t*)(ws + (4u<<20));          // 4..12MB O partials [4][4096][128] u32 (bf16 pairs)
  u16t*  xb   = (u16t*)(ws + (4u<<20));          // alias attB[0..2MB): conv->gemm only
  u16t*  QKV  = (u16t*)(ws + (12u<<20));         // 12..16MB [4096][512] bf16 (Q|K)
  u16t*  Vth  = (u16t*)(ws + (16u<<20));         // 16..18MB [256][4096] bf16 V^T
  float* Lp   = (float*)(ws + (18u<<20));        // 18..18.5MB L partials [4][8][4096]
  u16t*  Wtb  = (u16t*)(ws + (19u<<20));         // 19..19.5MB W^T bf16 (4 mats)
  float* bb   = (float*)(ws + (19u<<20) + (512u<<10)); // bias fp32 (768)

  hipMemsetAsync(A, 0, (2u<<20), stream);
  k0_kernel  <<<449,  256, 0, stream>>>(Wq,bq, Wk,bk, Wv,bv, Wo, x, Wtb, bb, xb, ei, A);
  k1_kernel  <<<4480, 256, 0, stream>>>(xb, Wtb, bb, QKV, Vth, A, MT);
  fattn_kernel<<<1024, 256, 0, stream>>>(MT, QKV, Vth, attB, Lp);
  outln_kernel<<<256,  256, 0, stream>>>(attB, Lp, Wtb + (size_t)3*256*256, bo, x, lnw, lnb, (float*)d_out);
}